// Round 8
// baseline (83.130 us; speedup 1.0000x reference)
//
#include <hip/hip_runtime.h>
#include <cmath>

#define B_N 512
#define T_N 50
#define GRIDN 13
#define A_N 9
#define P_N 1521          // 13*13*9
#define ROW 85            // 5 + 80 classes
#define NCLS 80
#define FPI (P_N * ROW)   // floats per image = 129285
#define CHUNKS 4
#define CHQ 8081          // quads per chunk: ceil(32324/4)

typedef float f32x4 __attribute__((ext_vector_type(4)));

struct Entry {
    int prior;
    float tx, ty, tw, th;
    unsigned int cls[3];   // 80-bit class one-hot mask
};

// ---------------------------------------------------------------------------
// Main kernel: grid = (CHUNKS, B) x 256 thr. Each block pure-streams a
// contiguous quarter-slab (129 KB) with plain float4 loads (2x unroll),
// extracting col-4 (conf) via incremental mod-85 tracking.
// Chunk-0 blocks additionally run the sparse phases AFTER their stream:
// entry build (wave 0, shfl dedup last-wins) + obj-prior corrections.
// ---------------------------------------------------------------------------
__global__ void __launch_bounds__(256)
main_kernel(const float* __restrict__ pred,
            const float* __restrict__ tgt,
            const float* __restrict__ anchors,
            float* __restrict__ S_part,   // [B][CHUNKS]
            float* __restrict__ corr)     // [B][4]: BX, LP, L1, CL
{
    __shared__ Entry ents[T_N];
    __shared__ int   s_cnt;
    __shared__ float red[4][5];

    const int  tid  = threadIdx.x;
    const int  lane = tid & 63;
    const int  b    = blockIdx.y;
    const int  c    = blockIdx.x;
    const bool isc0 = (c == 0);

    // ---- has flag: each wave ballots independently (no barrier) ----
    const float* tb = tgt + (size_t)b * T_N * 6;
    float confv = (lane < T_N) ? tb[lane * 6 + 4] : 0.0f;
    const bool hasv = (__ballot(confv > 0.0f) != 0ull);
    const float sgn = hasv ? 1.0f : -1.0f;

    // ---- dense conf stream over this chunk's quads ----
    // slab starts (b%4) floats off 16B; skip a0 head floats (cols 0..2, never
    // col 4); <4-float slab tail is cols 82..84 of the last row, also safe.
    const float* slab = pred + (size_t)b * FPI;
    const int a0 = (4 - (b & 3)) & 3;
    const int NQ = (FPI - a0) >> 2;
    const f32x4* qp = (const f32x4*)(slab + a0);

    auto amod = [](int cc, int k) { cc += k; return (cc >= 85) ? cc - 85 : cc; };
    auto term = [&](f32x4 v, int cc) -> float {
        // quad holds col 4 iff cc in [1,4], at element 4-cc
        if ((unsigned)(cc - 1) > 3u) return 0.0f;
        float x = v[4 - cc];
        float z = sgn * x;   // has: z=x -> -softplus(x)=log(1-sig); empty: z=-x
        float sp = fmaxf(z, 0.0f) + __logf(1.0f + __expf(-fabsf(z)));
        return fmaxf(-sp, -100.0f);
    };

    const int q0   = c * CHQ + tid;
    const int qend = ((c + 1) * CHQ < NQ) ? (c + 1) * CHQ : NQ;
    int   c0 = (a0 + (q0 << 2)) % 85;    // col of quad elem 0
    float s0 = 0.f, s1 = 0.f;
    int   q  = q0;
    // strides: +256 quads = 1024 floats = 4 (mod 85); +512 quads = 8 (mod 85)
    for (; q + 256 < qend; q += 512) {
        f32x4 v0 = qp[q];
        f32x4 v1 = qp[q + 256];
        s0 += term(v0, c0);
        s1 += term(v1, amod(c0, 4));
        c0 = amod(c0, 8);
    }
    for (; q < qend; q += 256) {
        s0 += term(qp[q], c0);
        c0 = amod(c0, 4);
    }
    float s_main = s0 + s1;

    // ---- block reduce S and write chunk partial ----
    {
        float v = s_main;
        #pragma unroll
        for (int o = 32; o > 0; o >>= 1) v += __shfl_down(v, o, 64);
        if (lane == 0) red[tid >> 6][0] = v;
    }
    __syncthreads();
    if (tid == 0)
        S_part[(b << 2) + c] = red[0][0] + red[1][0] + red[2][0] + red[3][0];

    if (!isc0) return;

    // ================= sparse phases (chunk-0 blocks only) =================
    // ---- entry build (wave 0) ----
    if (tid < 64) {
        int   prior = -1;
        float txv = 0.f, tyv = 0.f, twv = 0.f, thv = 0.f;
        int   cls = 0;
        if (lane < T_N) {
            const float* t = tb + lane * 6;
            float x = t[0], y = t[1], w = t[2], h = t[3], conf = t[4];
            if (conf > 0.0f) {
                float tw_px = w * 1000.0f, th_px = h * 1000.0f;
                int best = 0; float bestv = -1.0f;
                #pragma unroll
                for (int a = 0; a < A_N; ++a) {
                    float aw = anchors[2*a], ah = anchors[2*a+1];
                    float inter = fminf(aw, tw_px) * fminf(ah, th_px);
                    float uni   = aw*ah + tw_px*th_px - inter;
                    float iou   = inter / (uni + 1e-16f);
                    if (iou > bestv) { bestv = iou; best = a; }  // first-max
                }
                int gx = (int)floorf(x * (float)GRIDN);
                int gy = (int)floorf(y * (float)GRIDN);
                prior = gy * (GRIDN * A_N) + gx * A_N + best;
                txv = x * (float)GRIDN - (float)gx;
                tyv = y * (float)GRIDN - (float)gy;
                float aw = anchors[2*best], ah = anchors[2*best+1];
                twv = logf(w * (float)GRIDN / aw + 1e-16f);
                thv = logf(h * (float)GRIDN / ah + 1e-16f);
                cls = (int)t[5];
            }
        }
        bool valid = (prior >= 0);
        unsigned int m0 = 0, m1 = 0, m2 = 0;
        bool laterdup = false;
        #pragma unroll
        for (int j = 0; j < T_N; ++j) {
            int pj = __shfl(prior, j, 64);
            int cj = __shfl(cls,   j, 64);
            if (valid && pj == prior) {
                if (j > lane) laterdup = true;   // last-wins scatter
                if (cj < 32)      m0 |= 1u << cj;
                else if (cj < 64) m1 |= 1u << (cj - 32);
                else              m2 |= 1u << (cj - 64);
            }
        }
        bool winner = valid && !laterdup;
        unsigned long long mask = __ballot(winner);
        if (winner) {
            int idx = __popcll(mask & ((1ull << lane) - 1ull));
            Entry* e = &ents[idx];
            e->prior = prior;
            e->tx = txv; e->ty = tyv; e->tw = twv; e->th = thv;
            e->cls[0] = m0; e->cls[1] = m1; e->cls[2] = m2;
        }
        if (lane == 0) s_cnt = __popcll(mask);
    }
    __syncthreads();

    const int cnt = s_cnt;

    // ---- obj corrections (2 groups of 128) ----
    float cls_s = 0.0f, box_s = 0.0f, objlp = 0.0f, objl1 = 0.0f;
    {
        const int gid = tid >> 7;       // 0..1
        const int lt  = tid & 127;
        for (int e = gid; e < cnt; e += 2) {
            Entry en = ents[e];
            const float* row = slab + (size_t)en.prior * ROW;
            if (lt < NCLS) {
                float x  = row[5 + lt];
                float s  = 1.0f / (1.0f + __expf(-x));
                float lp = fmaxf(__logf(s),        -100.0f);
                float l1 = fmaxf(__logf(1.0f - s), -100.0f);
                float tc = ((en.cls[lt >> 5] >> (lt & 31)) & 1u) ? 1.0f : 0.0f;
                cls_s += -(tc * lp + (1.0f - tc) * l1);
            } else if (lt == NCLS) {
                float x = row[4];
                float s = 1.0f / (1.0f + __expf(-x));
                objlp += fmaxf(__logf(s),        -100.0f);
                objl1 += fmaxf(__logf(1.0f - s), -100.0f);
            } else if (lt == NCLS + 1) {
                float d0 = row[0] - en.tx;
                float d1 = row[1] - en.ty;
                float d2 = row[2] - en.tw;
                float d3 = row[3] - en.th;
                box_s += d0*d0 + d1*d1 + d2*d2 + d3*d3;
            }
        }
    }

    // ---- reduce 4 correction sums ----
    float v1 = objl1, v2 = objlp, v3 = box_s, v4 = cls_s;
    #pragma unroll
    for (int o = 32; o > 0; o >>= 1) {
        v1 += __shfl_down(v1, o, 64);
        v2 += __shfl_down(v2, o, 64);
        v3 += __shfl_down(v3, o, 64);
        v4 += __shfl_down(v4, o, 64);
    }
    const int w = tid >> 6;
    if (lane == 0) { red[w][1] = v1; red[w][2] = v2; red[w][3] = v3; red[w][4] = v4; }
    __syncthreads();
    if (tid == 0) {
        float L1 = red[0][1] + red[1][1] + red[2][1] + red[3][1];
        float LP = red[0][2] + red[1][2] + red[2][2] + red[3][2];
        float BX = red[0][3] + red[1][3] + red[2][3] + red[3][3];
        float CL = red[0][4] + red[1][4] + red[2][4] + red[3][4];
        float* o = corr + (size_t)b * 4;
        o[0] = BX; o[1] = LP; o[2] = L1; o[3] = CL;
    }
}

// ---------------------------------------------------------------------------
// Finalize: reduce 512 images' partials -> 5 outputs.
// ---------------------------------------------------------------------------
__global__ void __launch_bounds__(256)
finalize_kernel(const float* __restrict__ S_part,
                const float* __restrict__ corr,
                float* __restrict__ out)
{
    __shared__ float red[4][4];
    const int tid  = threadIdx.x;
    const int lane = tid & 63;

    float a_box = 0, a_obj = 0, a_noobj = 0, a_cls = 0;
    for (int b = tid; b < B_N; b += 256) {
        float4 s4 = ((const float4*)S_part)[b];
        float  S  = (s4.x + s4.y) + (s4.z + s4.w);
        float4 cr = ((const float4*)corr)[b];     // BX, LP, L1, CL
        a_box   += 5.0f * cr.x;
        a_obj   += -cr.y;
        a_noobj += -100.0f * (S - cr.z);          // empty branch ok (L1==0)
        a_cls   += cr.w;
    }
    #pragma unroll
    for (int o = 32; o > 0; o >>= 1) {
        a_box   += __shfl_down(a_box,   o, 64);
        a_obj   += __shfl_down(a_obj,   o, 64);
        a_noobj += __shfl_down(a_noobj, o, 64);
        a_cls   += __shfl_down(a_cls,   o, 64);
    }
    const int w = tid >> 6;
    if (lane == 0) { red[w][0] = a_box; red[w][1] = a_obj; red[w][2] = a_noobj; red[w][3] = a_cls; }
    __syncthreads();
    if (tid == 0) {
        const float invB = 1.0f / (float)B_N;
        float box   = (red[0][0] + red[1][0] + red[2][0] + red[3][0]) * invB;
        float obj   = (red[0][1] + red[1][1] + red[2][1] + red[3][1]) * invB;
        float noobj = (red[0][2] + red[1][2] + red[2][2] + red[3][2]) * invB;
        float cls   = (red[0][3] + red[1][3] + red[2][3] + red[3][3]) * invB;
        out[0] = box + obj + noobj + cls;
        out[1] = box;
        out[2] = obj;
        out[3] = noobj;
        out[4] = cls;
    }
}

extern "C" void kernel_launch(void* const* d_in, const int* in_sizes, int n_in,
                              void* d_out, int out_size, void* d_ws, size_t ws_size,
                              hipStream_t stream)
{
    const float* pred    = (const float*)d_in[0];  // [512,1521,85]
    const float* tgt     = (const float*)d_in[1];  // [512,50,6]
    const float* anchors = (const float*)d_in[2];  // [9,2]
    float* out = (float*)d_out;                    // 5 floats

    char*  ws     = (char*)d_ws;
    float* S_part = (float*)ws;                    // 512*4 floats
    float* corr   = (float*)(ws + 8192);           // 512*4 floats

    main_kernel<<<dim3(CHUNKS, B_N), dim3(256), 0, stream>>>(pred, tgt, anchors, S_part, corr);
    finalize_kernel<<<dim3(1), dim3(256), 0, stream>>>(S_part, corr, out);
}

// Round 9
// 70.440 us; speedup vs baseline: 1.1802x; 1.1802x over previous
//
#include <hip/hip_runtime.h>
#include <cmath>

#define B_N 512
#define T_N 50
#define GRIDN 13
#define A_N 9
#define P_N 1521          // 13*13*9
#define ROW 85            // 5 + 80 classes
#define NCLS 80
#define FPI (P_N * ROW)   // floats per image = 129285
#define NTHR 1024
#define WQ 2048           // quads per window = 32 KB

typedef float f32x4 __attribute__((ext_vector_type(4)));

struct Entry {
    int prior;
    float tx, ty, tw, th;
    unsigned int cls[3];   // 80-bit class one-hot mask
};

// ---------------------------------------------------------------------------
// Main kernel: one block (1024 thr) per image.
//   Stream/gather pipeline over 32KB windows:
//     - stream window w with pure float4 loads (kept alive via empty asm,
//       no attached VALU) -> lines land in L2;
//     - gather window w-1's ~96 conf values via direct scattered loads
//       (L2 hits) and run softplus ONLY on those (778k total vs 16.5M quads).
//   Then: wave 0 builds the entry list (shfl dedup, last-wins);
//         8 groups x 128 thr do obj-prior corrections.
//   Epilogue: block reduce 5 sums -> part[b][5]. No atomics.
// ---------------------------------------------------------------------------
__global__ void __launch_bounds__(NTHR)
main_kernel(const float* __restrict__ pred,
            const float* __restrict__ tgt,
            const float* __restrict__ anchors,
            float* __restrict__ part)      // [B][5]: S, L1, LP, BX, CL
{
    __shared__ Entry ents[T_N];
    __shared__ int   s_cnt;
    __shared__ float red[16][5];

    const int tid  = threadIdx.x;
    const int lane = tid & 63;
    const int b    = blockIdx.x;

    // ---------------- has flag (per-wave ballot, no barrier) --------------
    const float* tb = tgt + (size_t)b * T_N * 6;
    float confv = (lane < T_N) ? tb[lane * 6 + 4] : 0.0f;
    const bool hasv = (__ballot(confv > 0.0f) != 0ull);
    const float sgn = hasv ? 1.0f : -1.0f;

    // ---------------- windowed stream + gather ----------------------------
    // slab starts (b%4) floats off 16B; a0 head floats are cols 0..2 and the
    // <4-float tail is cols 82..84 of the last row — neither is col 4 (conf).
    const float* slab = pred + (size_t)b * FPI;
    const int a0 = (4 - (b & 3)) & 3;
    const int NQ = (FPI - a0) >> 2;
    const f32x4* qp = (const f32x4*)(slab + a0);
    const int nw = (NQ + WQ - 1) / WQ;     // 16

    float s_main = 0.0f;
    auto gather = [&](int w) {
        int F0 = a0 + ((w * WQ) << 2);
        int qe = (w + 1) * WQ; if (qe > NQ) qe = NQ;
        int F1 = a0 + (qe << 2);
        int p_lo = (F0 + 80) / 85;         // ceil((F0-4)/85)
        int p_hi = (F1 + 80) / 85;
        if (tid < p_hi - p_lo) {
            int p = p_lo + tid;
            float x = slab[85 * p + 4];    // L2 hit: streamed last window
            float z = sgn * x;             // has: log(1-sig)=-sp(x); else -sp(-x)
            float sp = fmaxf(z, 0.0f) + __logf(1.0f + __expf(-fabsf(z)));
            s_main += fmaxf(-sp, -100.0f);
        }
    };

    for (int w = 0; w < nw; ++w) {
        const int base = w * WQ;
        const int q0 = base + tid;
        const int q1 = base + tid + NTHR;
        f32x4 v0 = {0.f, 0.f, 0.f, 0.f};
        f32x4 v1 = {0.f, 0.f, 0.f, 0.f};
        if (q0 < NQ) v0 = qp[q0];
        if (q1 < NQ) v1 = qp[q1];
        if (w > 0) gather(w - 1);
        asm volatile("" :: "v"(v0), "v"(v1));   // keep stream loads alive
    }
    gather(nw - 1);

    // ---------------- entry build (wave 0) --------------------------------
    if (tid < 64) {
        int   prior = -1;
        float txv = 0.f, tyv = 0.f, twv = 0.f, thv = 0.f;
        int   cls = 0;
        if (lane < T_N) {
            const float* t = tb + lane * 6;
            float x = t[0], y = t[1], w = t[2], h = t[3], conf = t[4];
            if (conf > 0.0f) {
                float tw_px = w * 1000.0f, th_px = h * 1000.0f;
                int best = 0; float bestv = -1.0f;
                #pragma unroll
                for (int a = 0; a < A_N; ++a) {
                    float aw = anchors[2*a], ah = anchors[2*a+1];
                    float inter = fminf(aw, tw_px) * fminf(ah, th_px);
                    float uni   = aw*ah + tw_px*th_px - inter;
                    float iou   = inter / (uni + 1e-16f);
                    if (iou > bestv) { bestv = iou; best = a; }  // first-max
                }
                int gx = (int)floorf(x * (float)GRIDN);
                int gy = (int)floorf(y * (float)GRIDN);
                prior = gy * (GRIDN * A_N) + gx * A_N + best;
                txv = x * (float)GRIDN - (float)gx;
                tyv = y * (float)GRIDN - (float)gy;
                float aw = anchors[2*best], ah = anchors[2*best+1];
                twv = logf(w * (float)GRIDN / aw + 1e-16f);
                thv = logf(h * (float)GRIDN / ah + 1e-16f);
                cls = (int)t[5];
            }
        }
        bool valid = (prior >= 0);
        unsigned int m0 = 0, m1 = 0, m2 = 0;
        bool laterdup = false;
        #pragma unroll
        for (int j = 0; j < T_N; ++j) {
            int pj = __shfl(prior, j, 64);
            int cj = __shfl(cls,   j, 64);
            if (valid && pj == prior) {
                if (j > lane) laterdup = true;   // last-wins scatter
                if (cj < 32)      m0 |= 1u << cj;
                else if (cj < 64) m1 |= 1u << (cj - 32);
                else              m2 |= 1u << (cj - 64);
            }
        }
        bool winner = valid && !laterdup;
        unsigned long long mask = __ballot(winner);
        if (winner) {
            int idx = __popcll(mask & ((1ull << lane) - 1ull));
            Entry* e = &ents[idx];
            e->prior = prior;
            e->tx = txv; e->ty = tyv; e->tw = twv; e->th = thv;
            e->cls[0] = m0; e->cls[1] = m1; e->cls[2] = m2;
        }
        if (lane == 0) s_cnt = __popcll(mask);
    }
    __syncthreads();

    const int cnt = s_cnt;

    // ---------------- obj corrections (8 groups of 128) -------------------
    float cls_s = 0.0f, box_s = 0.0f, objlp = 0.0f, objl1 = 0.0f;
    {
        const int gid = tid >> 7;       // 0..7
        const int lt  = tid & 127;
        for (int e = gid; e < cnt; e += 8) {
            Entry en = ents[e];
            const float* row = slab + (size_t)en.prior * ROW;
            if (lt < NCLS) {
                float x  = row[5 + lt];
                float s  = 1.0f / (1.0f + __expf(-x));
                float lp = fmaxf(__logf(s),        -100.0f);
                float l1 = fmaxf(__logf(1.0f - s), -100.0f);
                float tc = ((en.cls[lt >> 5] >> (lt & 31)) & 1u) ? 1.0f : 0.0f;
                cls_s += -(tc * lp + (1.0f - tc) * l1);
            } else if (lt == NCLS) {
                float x = row[4];
                float s = 1.0f / (1.0f + __expf(-x));
                objlp += fmaxf(__logf(s),        -100.0f);
                objl1 += fmaxf(__logf(1.0f - s), -100.0f);
            } else if (lt == NCLS + 1) {
                float d0 = row[0] - en.tx;
                float d1 = row[1] - en.ty;
                float d2 = row[2] - en.tw;
                float d3 = row[3] - en.th;
                box_s += d0*d0 + d1*d1 + d2*d2 + d3*d3;
            }
        }
    }

    // ---------------- epilogue: block reduce 5 sums -----------------------
    float v0 = s_main, v1 = objl1, v2 = objlp, v3 = box_s, v4 = cls_s;
    #pragma unroll
    for (int o = 32; o > 0; o >>= 1) {
        v0 += __shfl_down(v0, o, 64);
        v1 += __shfl_down(v1, o, 64);
        v2 += __shfl_down(v2, o, 64);
        v3 += __shfl_down(v3, o, 64);
        v4 += __shfl_down(v4, o, 64);
    }
    const int w = tid >> 6;
    if (lane == 0) {
        red[w][0] = v0; red[w][1] = v1; red[w][2] = v2;
        red[w][3] = v3; red[w][4] = v4;
    }
    __syncthreads();
    if (tid < 5) {
        float s = 0.0f;
        #pragma unroll
        for (int ww = 0; ww < 16; ++ww) s += red[ww][tid];
        part[(size_t)b * 5 + tid] = s;        // S, L1, LP, BX, CL
    }
}

// ---------------------------------------------------------------------------
// Finalize: reduce 512 images' partials -> 5 outputs.
// ---------------------------------------------------------------------------
__global__ void __launch_bounds__(256)
finalize_kernel(const float* __restrict__ part, float* __restrict__ out)
{
    __shared__ float red[4][4];
    const int tid  = threadIdx.x;
    const int lane = tid & 63;

    float a_box = 0, a_obj = 0, a_noobj = 0, a_cls = 0;
    for (int b = tid; b < B_N; b += 256) {
        const float* p = part + (size_t)b * 5;
        float S  = p[0];
        float L1 = p[1];
        float LP = p[2];
        float BX = p[3];
        float CL = p[4];
        a_box   += 5.0f * BX;
        a_obj   += -LP;
        a_noobj += -100.0f * (S - L1);   // valid for empty branch too (L1==0)
        a_cls   += CL;
    }
    #pragma unroll
    for (int o = 32; o > 0; o >>= 1) {
        a_box   += __shfl_down(a_box,   o, 64);
        a_obj   += __shfl_down(a_obj,   o, 64);
        a_noobj += __shfl_down(a_noobj, o, 64);
        a_cls   += __shfl_down(a_cls,   o, 64);
    }
    const int w = tid >> 6;
    if (lane == 0) { red[w][0] = a_box; red[w][1] = a_obj; red[w][2] = a_noobj; red[w][3] = a_cls; }
    __syncthreads();
    if (tid == 0) {
        const float invB = 1.0f / (float)B_N;
        float box   = (red[0][0] + red[1][0] + red[2][0] + red[3][0]) * invB;
        float obj   = (red[0][1] + red[1][1] + red[2][1] + red[3][1]) * invB;
        float noobj = (red[0][2] + red[1][2] + red[2][2] + red[3][2]) * invB;
        float cls   = (red[0][3] + red[1][3] + red[2][3] + red[3][3]) * invB;
        out[0] = box + obj + noobj + cls;
        out[1] = box;
        out[2] = obj;
        out[3] = noobj;
        out[4] = cls;
    }
}

extern "C" void kernel_launch(void* const* d_in, const int* in_sizes, int n_in,
                              void* d_out, int out_size, void* d_ws, size_t ws_size,
                              hipStream_t stream)
{
    const float* pred    = (const float*)d_in[0];  // [512,1521,85]
    const float* tgt     = (const float*)d_in[1];  // [512,50,6]
    const float* anchors = (const float*)d_in[2];  // [9,2]
    float* out  = (float*)d_out;                   // 5 floats
    float* part = (float*)d_ws;                    // 512*5 floats

    main_kernel<<<dim3(B_N), dim3(NTHR), 0, stream>>>(pred, tgt, anchors, part);
    finalize_kernel<<<dim3(1), dim3(256), 0, stream>>>(part, out);
}

// Round 10
// 63.764 us; speedup vs baseline: 1.3037x; 1.1047x over previous
//
#include <hip/hip_runtime.h>
#include <cmath>

#define B_N 512
#define T_N 50
#define GRIDN 13
#define A_N 9
#define P_N 1521          // 13*13*9
#define ROW 85            // 5 + 80 classes
#define NCLS 80
#define FPI (P_N * ROW)   // floats per image = 129285
#define NTHR 1024
#define G_HALF 256        // images per regime
#define DTHR 768          // dense threads (waves 0..11)

typedef float f32x4 __attribute__((ext_vector_type(4)));

struct Entry {
    int prior;
    float tx, ty, tw, th;
    unsigned int cls[3];   // 80-bit class one-hot mask
};

// max(-softplus(z), -100):  z=x -> log(1-sigmoid(x));  z=-x -> log(sigmoid(x))
__device__ __forceinline__ float bce_neg(float z) {
    float sp = fmaxf(z, 0.0f) + __logf(1.0f + __expf(-fabsf(z)));
    return fmaxf(-sp, -100.0f);
}

// wave-parallel entry build (shfl dedup, last-wins .at[].set semantics)
__device__ __forceinline__ void build_entries(const float* __restrict__ tb,
                                              const float* __restrict__ anchors,
                                              int lane, Entry* ents, int* s_cnt)
{
    int   prior = -1;
    float txv = 0.f, tyv = 0.f, twv = 0.f, thv = 0.f;
    int   cls = 0;
    if (lane < T_N) {
        const float* t = tb + lane * 6;
        float x = t[0], y = t[1], w = t[2], h = t[3], conf = t[4];
        if (conf > 0.0f) {
            float tw_px = w * 1000.0f, th_px = h * 1000.0f;
            int best = 0; float bestv = -1.0f;
            #pragma unroll
            for (int a = 0; a < A_N; ++a) {
                float aw = anchors[2*a], ah = anchors[2*a+1];
                float inter = fminf(aw, tw_px) * fminf(ah, th_px);
                float uni   = aw*ah + tw_px*th_px - inter;
                float iou   = inter / (uni + 1e-16f);
                if (iou > bestv) { bestv = iou; best = a; }   // first-max argmax
            }
            int gx = (int)floorf(x * (float)GRIDN);
            int gy = (int)floorf(y * (float)GRIDN);
            prior = gy * (GRIDN * A_N) + gx * A_N + best;
            txv = x * (float)GRIDN - (float)gx;
            tyv = y * (float)GRIDN - (float)gy;
            float aw = anchors[2*best], ah = anchors[2*best+1];
            twv = logf(w * (float)GRIDN / aw + 1e-16f);
            thv = logf(h * (float)GRIDN / ah + 1e-16f);
            cls = (int)t[5];
        }
    }
    bool valid = (prior >= 0);
    unsigned int m0 = 0, m1 = 0, m2 = 0;
    bool laterdup = false;
    #pragma unroll
    for (int j = 0; j < T_N; ++j) {
        int pj = __shfl(prior, j, 64);
        int cj = __shfl(cls,   j, 64);
        if (valid && pj == prior) {
            if (j > lane) laterdup = true;
            if (cj < 32)      m0 |= 1u << cj;
            else if (cj < 64) m1 |= 1u << (cj - 32);
            else              m2 |= 1u << (cj - 64);
        }
    }
    bool winner = valid && !laterdup;
    unsigned long long mask = __ballot(winner);
    if (winner) {
        int idx = __popcll(mask & ((1ull << lane) - 1ull));
        Entry* e = &ents[idx];
        e->prior = prior;
        e->tx = txv; e->ty = tyv; e->tw = twv; e->th = thv;
        e->cls[0] = m0; e->cls[1] = m1; e->cls[2] = m2;
    }
    if (lane == 0) *s_cnt = __popcll(mask);
}

// ---------------------------------------------------------------------------
// Hybrid main kernel: 256 blocks x 1024 thr (1/CU). Block k:
//   waves 0..11 : dense float4 stream of image k's slab (BW-bound regime)
//   waves 12..15: scattered conf-column gather of image k+256 (latency regime)
// Per-wave vmcnt counters keep the two access patterns decoupled.
// Then: entry builds (waves 0 and 12), corrections (half-block per image),
// one 10-slot block reduction -> part rows for both images. No atomics.
// ---------------------------------------------------------------------------
__global__ void __launch_bounds__(NTHR)
main_kernel(const float* __restrict__ pred,
            const float* __restrict__ tgt,
            const float* __restrict__ anchors,
            float* __restrict__ part)      // [B][5]: S, L1, LP, BX, CL
{
    __shared__ Entry ents_d[T_N], ents_s[T_N];
    __shared__ int   cnt_d, cnt_s;
    __shared__ float red[16][10];

    const int tid  = threadIdx.x;
    const int lane = tid & 63;
    const int wv   = tid >> 6;
    const int bd   = blockIdx.x;            // dense image
    const int bs   = blockIdx.x + G_HALF;   // scattered image

    const float* tbd   = tgt + (size_t)bd * T_N * 6;
    const float* tbs   = tgt + (size_t)bs * T_N * 6;
    const float* slabd = pred + (size_t)bd * FPI;
    const float* slabs = pred + (size_t)bs * FPI;

    float confd = (lane < T_N) ? tbd[lane * 6 + 4] : 0.0f;
    const float sgnd = (__ballot(confd > 0.0f) != 0ull) ? 1.0f : -1.0f;
    float confs = (lane < T_N) ? tbs[lane * 6 + 4] : 0.0f;
    const float sgns = (__ballot(confs > 0.0f) != 0ull) ? 1.0f : -1.0f;

    float acc[10];
    #pragma unroll
    for (int i = 0; i < 10; ++i) acc[i] = 0.0f;

    if (tid < DTHR) {
        // ---- dense stream of image bd ----
        // slab starts (bd%4) floats off 16B; skipped head floats are cols
        // 0..2, tail floats cols 82..84 — never col 4 (conf).
        const int a0 = (4 - (bd & 3)) & 3;
        const int NQ = (FPI - a0) >> 2;
        const f32x4* qp = (const f32x4*)(slabd + a0);
        int c0 = (a0 + (tid << 2)) % 85;    // col of quad elem 0
        float s = 0.0f;
        for (int q = tid; q < NQ; q += DTHR) {   // +768 quads == +12 (mod 85)
            f32x4 v = qp[q];
            if ((unsigned)(c0 - 1) <= 3u)        // quad holds col 4 at 4-c0
                s += bce_neg(sgnd * v[4 - c0]);
            c0 += 12; if (c0 >= 85) c0 -= 85;
        }
        acc[0] = s;
    } else {
        // ---- scattered conf gather of image bs (6 independent loads) ----
        const int stid = tid - DTHR;             // 0..255
        float xs[6];
        #pragma unroll
        for (int k = 0; k < 6; ++k) {
            int p = stid + (k << 8);
            xs[k] = (p < P_N) ? slabs[85 * p + 4] : 0.0f;
        }
        float s = 0.0f;
        #pragma unroll
        for (int k = 0; k < 6; ++k) {
            int p = stid + (k << 8);
            if (p < P_N) s += bce_neg(sgns * xs[k]);
        }
        acc[5] = s;
    }

    // ---- entry builds ----
    if (wv == 0)  build_entries(tbd, anchors, lane, ents_d, &cnt_d);
    if (wv == 12) build_entries(tbs, anchors, lane, ents_s, &cnt_s);
    __syncthreads();

    // ---- obj corrections: threads 0..511 -> bd, 512..1023 -> bs ----
    {
        const bool   lo   = (tid < 512);
        const float* slab = lo ? slabd : slabs;
        const Entry* ents = lo ? ents_d : ents_s;
        const int    cnt  = lo ? cnt_d  : cnt_s;
        const int    gid  = (tid >> 7) & 3;     // 0..3 within half
        const int    lt   = tid & 127;
        float cls_s = 0.f, box_s = 0.f, objlp = 0.f, objl1 = 0.f;
        for (int e = gid; e < cnt; e += 4) {
            Entry en = ents[e];
            const float* row = slab + (size_t)en.prior * ROW;
            if (lt < NCLS) {
                float x  = row[5 + lt];
                float sg = 1.0f / (1.0f + __expf(-x));
                float lp = fmaxf(__logf(sg),        -100.0f);
                float l1 = fmaxf(__logf(1.0f - sg), -100.0f);
                float tc = ((en.cls[lt >> 5] >> (lt & 31)) & 1u) ? 1.0f : 0.0f;
                cls_s += -(tc * lp + (1.0f - tc) * l1);
            } else if (lt == NCLS) {
                float x  = row[4];
                float sg = 1.0f / (1.0f + __expf(-x));
                objlp += fmaxf(__logf(sg),        -100.0f);
                objl1 += fmaxf(__logf(1.0f - sg), -100.0f);
            } else if (lt == NCLS + 1) {
                float d0 = row[0] - en.tx;
                float d1 = row[1] - en.ty;
                float d2 = row[2] - en.tw;
                float d3 = row[3] - en.th;
                box_s += d0*d0 + d1*d1 + d2*d2 + d3*d3;
            }
        }
        const int off = lo ? 1 : 6;
        acc[off + 0] = objl1;   // L1
        acc[off + 1] = objlp;   // LP
        acc[off + 2] = box_s;   // BX
        acc[off + 3] = cls_s;   // CL
    }

    // ---- block reduce 10 slots ----
    #pragma unroll
    for (int o = 32; o > 0; o >>= 1) {
        #pragma unroll
        for (int i = 0; i < 10; ++i) acc[i] += __shfl_down(acc[i], o, 64);
    }
    if (lane == 0) {
        #pragma unroll
        for (int i = 0; i < 10; ++i) red[wv][i] = acc[i];
    }
    __syncthreads();
    if (tid < 10) {
        float s = 0.0f;
        #pragma unroll
        for (int w = 0; w < 16; ++w) s += red[w][tid];
        if (tid < 5) part[(size_t)bd * 5 + tid]       = s;
        else         part[(size_t)bs * 5 + (tid - 5)] = s;
    }
}

// ---------------------------------------------------------------------------
// Finalize: reduce 512 images' partials -> 5 outputs.
// ---------------------------------------------------------------------------
__global__ void __launch_bounds__(256)
finalize_kernel(const float* __restrict__ part, float* __restrict__ out)
{
    __shared__ float red[4][4];
    const int tid  = threadIdx.x;
    const int lane = tid & 63;

    float a_box = 0, a_obj = 0, a_noobj = 0, a_cls = 0;
    for (int b = tid; b < B_N; b += 256) {
        const float* p = part + (size_t)b * 5;
        float S  = p[0];
        float L1 = p[1];
        float LP = p[2];
        float BX = p[3];
        float CL = p[4];
        a_box   += 5.0f * BX;
        a_obj   += -LP;
        a_noobj += -100.0f * (S - L1);   // valid for empty branch too (L1==0)
        a_cls   += CL;
    }
    #pragma unroll
    for (int o = 32; o > 0; o >>= 1) {
        a_box   += __shfl_down(a_box,   o, 64);
        a_obj   += __shfl_down(a_obj,   o, 64);
        a_noobj += __shfl_down(a_noobj, o, 64);
        a_cls   += __shfl_down(a_cls,   o, 64);
    }
    const int w = tid >> 6;
    if (lane == 0) { red[w][0] = a_box; red[w][1] = a_obj; red[w][2] = a_noobj; red[w][3] = a_cls; }
    __syncthreads();
    if (tid == 0) {
        const float invB = 1.0f / (float)B_N;
        float box   = (red[0][0] + red[1][0] + red[2][0] + red[3][0]) * invB;
        float obj   = (red[0][1] + red[1][1] + red[2][1] + red[3][1]) * invB;
        float noobj = (red[0][2] + red[1][2] + red[2][2] + red[3][2]) * invB;
        float cls   = (red[0][3] + red[1][3] + red[2][3] + red[3][3]) * invB;
        out[0] = box + obj + noobj + cls;
        out[1] = box;
        out[2] = obj;
        out[3] = noobj;
        out[4] = cls;
    }
}

extern "C" void kernel_launch(void* const* d_in, const int* in_sizes, int n_in,
                              void* d_out, int out_size, void* d_ws, size_t ws_size,
                              hipStream_t stream)
{
    const float* pred    = (const float*)d_in[0];  // [512,1521,85]
    const float* tgt     = (const float*)d_in[1];  // [512,50,6]
    const float* anchors = (const float*)d_in[2];  // [9,2]
    float* out  = (float*)d_out;                   // 5 floats
    float* part = (float*)d_ws;                    // 512*5 floats

    main_kernel<<<dim3(G_HALF), dim3(NTHR), 0, stream>>>(pred, tgt, anchors, part);
    finalize_kernel<<<dim3(1), dim3(256), 0, stream>>>(part, out);
}

// Round 11
// 52.351 us; speedup vs baseline: 1.5879x; 1.2180x over previous
//
#include <hip/hip_runtime.h>
#include <cmath>

#define B_N 512
#define T_N 50
#define GRIDN 13
#define A_N 9
#define P_N 1521          // 13*13*9
#define ROW 85            // 5 + 80 classes
#define NCLS 80

struct Entry {
    int prior;
    float tx, ty, tw, th;
    unsigned int cls[3];   // 80-bit class one-hot mask
};                          // 32 bytes

// ---------------------------------------------------------------------------
// Fused per-image kernel: one block (256 thr) per image.
//   Phase A (wave 0): target assignment -> Entry list in LDS.
//   Phase B (all):    dense conf-column scan (grid-stride over P).
//   Phase C (2 half-blocks): per-obj-prior correction (cls BCE / obj / box).
//   Epilogue: block reduce, thread 0 writes per-image partial losses to ws.
// No global atomics anywhere.
// ---------------------------------------------------------------------------
__global__ void __launch_bounds__(256)
main_kernel(const float* __restrict__ pred,
            const float* __restrict__ tgt,
            const float* __restrict__ anchors,
            float* __restrict__ part)     // [B][4]: box, objlp, S-objl1, cls
{
    __shared__ Entry ents[T_N];
    __shared__ int   s_cnt;
    __shared__ float red[4][5];

    const int tid  = threadIdx.x;
    const int lane = tid & 63;
    const int b    = blockIdx.x;

    // ---------------- Phase A: build (wave 0 only) ----------------
    if (tid < 64) {
        int   prior = -1;
        float txv = 0.f, tyv = 0.f, twv = 0.f, thv = 0.f;
        int   cls = 0;

        if (lane < T_N) {
            const float* t = tgt + ((size_t)b * T_N + lane) * 6;
            float x = t[0], y = t[1], w = t[2], h = t[3], conf = t[4];
            if (conf > 0.0f) {
                float tw_px = w * 1000.0f, th_px = h * 1000.0f;
                int best = 0; float bestv = -1.0f;
                #pragma unroll
                for (int a = 0; a < A_N; ++a) {
                    float aw = anchors[2*a], ah = anchors[2*a+1];
                    float inter = fminf(aw, tw_px) * fminf(ah, th_px);
                    float uni   = aw*ah + tw_px*th_px - inter;
                    float iou   = inter / (uni + 1e-16f);
                    if (iou > bestv) { bestv = iou; best = a; }  // first-max argmax
                }
                int gx = (int)floorf(x * (float)GRIDN);
                int gy = (int)floorf(y * (float)GRIDN);
                prior = gy * (GRIDN * A_N) + gx * A_N + best;
                txv = x * (float)GRIDN - (float)gx;
                tyv = y * (float)GRIDN - (float)gy;
                float aw = anchors[2*best], ah = anchors[2*best+1];
                twv = logf(w * (float)GRIDN / aw + 1e-16f);
                thv = logf(h * (float)GRIDN / ah + 1e-16f);
                cls = (int)t[5];
            }
        }

        bool valid = (prior >= 0);
        unsigned int m0 = 0, m1 = 0, m2 = 0;
        bool laterdup = false;
        #pragma unroll
        for (int j = 0; j < T_N; ++j) {
            int pj = __shfl(prior, j, 64);
            int cj = __shfl(cls,   j, 64);
            if (valid && pj == prior) {
                if (j > lane) laterdup = true;   // last-wins .at[].set semantics
                if (cj < 32)      m0 |= 1u << cj;
                else if (cj < 64) m1 |= 1u << (cj - 32);
                else              m2 |= 1u << (cj - 64);
            }
        }
        bool winner = valid && !laterdup;
        unsigned long long mask = __ballot(winner);
        if (winner) {
            int idx = __popcll(mask & ((1ull << lane) - 1ull));
            Entry* e = &ents[idx];
            e->prior = prior;
            e->tx = txv; e->ty = tyv; e->tw = twv; e->th = thv;
            e->cls[0] = m0; e->cls[1] = m1; e->cls[2] = m2;
        }
        if (lane == 0) s_cnt = __popcll(mask);
    }
    __syncthreads();

    const int  cnt  = s_cnt;
    const bool hasv = (cnt > 0);

    // ---------------- Phase B: dense conf-column scan ----------------
    const float* pb = pred + (size_t)b * P_N * ROW;
    float s_main = 0.0f;
    #pragma unroll
    for (int p = tid; p < P_N; p += 256) {
        float x = pb[(size_t)p * ROW + 4];
        float s = 1.0f / (1.0f + __expf(-x));
        float v = hasv ? fmaxf(__logf(1.0f - s), -100.0f)
                       : fmaxf(__logf(s),        -100.0f);
        s_main += v;
    }

    // ---------------- Phase C: obj-prior corrections ----------------
    float cls_s = 0.0f, box_s = 0.0f, objlp = 0.0f, objl1 = 0.0f;
    {
        const int half = tid >> 7;      // 0 or 1
        const int lt   = tid & 127;
        for (int e = half; e < cnt; e += 2) {
            Entry en = ents[e];
            const float* row = pb + (size_t)en.prior * ROW;
            if (lt < NCLS) {
                float x  = row[5 + lt];
                float s  = 1.0f / (1.0f + __expf(-x));
                float lp = fmaxf(__logf(s),        -100.0f);
                float l1 = fmaxf(__logf(1.0f - s), -100.0f);
                float tc = ((en.cls[lt >> 5] >> (lt & 31)) & 1u) ? 1.0f : 0.0f;
                cls_s += -(tc * lp + (1.0f - tc) * l1);
            } else if (lt == NCLS) {
                float x = row[4];
                float s = 1.0f / (1.0f + __expf(-x));
                objlp += fmaxf(__logf(s),        -100.0f);
                objl1 += fmaxf(__logf(1.0f - s), -100.0f);
            } else if (lt == NCLS + 1) {
                float d0 = row[0] - en.tx;
                float d1 = row[1] - en.ty;
                float d2 = row[2] - en.tw;
                float d3 = row[3] - en.th;
                box_s += d0*d0 + d1*d1 + d2*d2 + d3*d3;
            }
        }
    }

    // ---------------- Epilogue: block reduce 5 values ----------------
    float v0 = s_main, v1 = objl1, v2 = objlp, v3 = box_s, v4 = cls_s;
    #pragma unroll
    for (int o = 32; o > 0; o >>= 1) {
        v0 += __shfl_down(v0, o, 64);
        v1 += __shfl_down(v1, o, 64);
        v2 += __shfl_down(v2, o, 64);
        v3 += __shfl_down(v3, o, 64);
        v4 += __shfl_down(v4, o, 64);
    }
    const int w = tid >> 6;
    if (lane == 0) {
        red[w][0] = v0; red[w][1] = v1; red[w][2] = v2;
        red[w][3] = v3; red[w][4] = v4;
    }
    __syncthreads();
    if (tid == 0) {
        float S  = red[0][0] + red[1][0] + red[2][0] + red[3][0];
        float L1 = red[0][1] + red[1][1] + red[2][1] + red[3][1];
        float LP = red[0][2] + red[1][2] + red[2][2] + red[3][2];
        float BX = red[0][3] + red[1][3] + red[2][3] + red[3][3];
        float CL = red[0][4] + red[1][4] + red[2][4] + red[3][4];
        float* o = part + (size_t)b * 4;
        o[0] = 5.0f * BX;              // box_i
        o[1] = -LP;                    // obj_i
        o[2] = -100.0f * (S - L1);     // noobj_i (valid for empty branch: L1==0)
        o[3] = CL;                     // cls_i
    }
}

// ---------------------------------------------------------------------------
// Finalize: reduce 512x4 partials -> 5 outputs (total, box, obj, noobj, cls)
// ---------------------------------------------------------------------------
__global__ void __launch_bounds__(256)
finalize_kernel(const float* __restrict__ part, float* __restrict__ out)
{
    __shared__ float red[4][4];
    const int tid  = threadIdx.x;
    const int lane = tid & 63;

    float a0 = 0, a1 = 0, a2 = 0, a3 = 0;
    for (int b = tid; b < B_N; b += 256) {
        const float* p = part + (size_t)b * 4;
        a0 += p[0]; a1 += p[1]; a2 += p[2]; a3 += p[3];
    }
    #pragma unroll
    for (int o = 32; o > 0; o >>= 1) {
        a0 += __shfl_down(a0, o, 64);
        a1 += __shfl_down(a1, o, 64);
        a2 += __shfl_down(a2, o, 64);
        a3 += __shfl_down(a3, o, 64);
    }
    const int w = tid >> 6;
    if (lane == 0) { red[w][0] = a0; red[w][1] = a1; red[w][2] = a2; red[w][3] = a3; }
    __syncthreads();
    if (tid == 0) {
        const float invB = 1.0f / (float)B_N;
        float box   = (red[0][0] + red[1][0] + red[2][0] + red[3][0]) * invB;
        float obj   = (red[0][1] + red[1][1] + red[2][1] + red[3][1]) * invB;
        float noobj = (red[0][2] + red[1][2] + red[2][2] + red[3][2]) * invB;
        float cls   = (red[0][3] + red[1][3] + red[2][3] + red[3][3]) * invB;
        out[0] = box + obj + noobj + cls;
        out[1] = box;
        out[2] = obj;
        out[3] = noobj;
        out[4] = cls;
    }
}

extern "C" void kernel_launch(void* const* d_in, const int* in_sizes, int n_in,
                              void* d_out, int out_size, void* d_ws, size_t ws_size,
                              hipStream_t stream)
{
    const float* pred    = (const float*)d_in[0];  // [512,1521,85]
    const float* tgt     = (const float*)d_in[1];  // [512,50,6]
    const float* anchors = (const float*)d_in[2];  // [9,2]
    float* out  = (float*)d_out;                   // 5 floats
    float* part = (float*)d_ws;                    // 512*4 floats

    main_kernel<<<dim3(B_N), dim3(256), 0, stream>>>(pred, tgt, anchors, part);
    finalize_kernel<<<dim3(1), dim3(256), 0, stream>>>(part, out);
}